// Round 1
// baseline (287.300 us; speedup 1.0000x reference)
//
#include <hip/hip_runtime.h>
#include <math.h>

#define N_NODES 2048
#define NCH 2
#define NET 3
#define NLAYER 2
#define NE 65536
#define TE 196608   /* NET*NE */
#define W_IN 256
#define W_OUT 64
#define NCLS 16
#define NTGT 512

// ---------------- setup kernels ----------------

__global__ void k_filt(const float* __restrict__ conv_w, float* __restrict__ filt) {
    int i = threadIdx.x;                       // i = l*NCH + c
    if (i < NLAYER * NCH) {
        float a = conv_w[i*NET+0], b = conv_w[i*NET+1], c = conv_w[i*NET+2];
        float m = fmaxf(a, fmaxf(b, c));
        float ea = expf(a-m), eb = expf(b-m), ec = expf(c-m);
        float s = ea + eb + ec;
        filt[i*NET+0] = ea/s; filt[i*NET+1] = eb/s; filt[i*NET+2] = ec/s;
    }
}

__global__ void k_zero(int* __restrict__ p, int n) {
    int i = blockIdx.x*blockDim.x + threadIdx.x;
    if (i < n) p[i] = 0;
}

__global__ void k_hist(const int* __restrict__ ei, int* __restrict__ counts) {
    int e = blockIdx.x*blockDim.x + threadIdx.x;
    if (e < TE) {
        int t = e >> 16, idx = e & 0xFFFF;
        int row = ei[t*2*NE + idx];
        atomicAdd(&counts[row], 1);
    }
}

__global__ void k_scan(const int* __restrict__ counts, int* __restrict__ row_start,
                       int* __restrict__ cursor) {
    __shared__ int part[256];
    int tid = threadIdx.x;
    int loc[8]; int s = 0;
    #pragma unroll
    for (int k = 0; k < 8; k++) { loc[k] = s; s += counts[tid*8 + k]; }
    part[tid] = s;
    __syncthreads();
    for (int off = 1; off < 256; off <<= 1) {
        int v = (tid >= off) ? part[tid - off] : 0;
        __syncthreads();
        part[tid] += v;
        __syncthreads();
    }
    int base = tid ? part[tid-1] : 0;
    #pragma unroll
    for (int k = 0; k < 8; k++) {
        int rs = base + loc[k];
        row_start[tid*8 + k] = rs;
        cursor[tid*8 + k] = rs;
    }
    if (tid == 255) row_start[N_NODES] = part[255];
}

__global__ void k_scatter(const int* __restrict__ ei, int* __restrict__ cursor,
                          int* __restrict__ perm) {
    int e = blockIdx.x*blockDim.x + threadIdx.x;
    if (e < TE) {
        int t = e >> 16, idx = e & 0xFFFF;
        int row = ei[t*2*NE + idx];
        int pos = atomicAdd(&cursor[row], 1);
        perm[pos] = e;
    }
}

__global__ void k_edges(const int* __restrict__ ei, const float* __restrict__ edge_value,
                        const int* __restrict__ perm, int* __restrict__ pcolt,
                        float* __restrict__ pev) {
    int j = blockIdx.x*blockDim.x + threadIdx.x;
    if (j < TE) {
        int pe = perm[j];
        int t = pe >> 16, idx = pe & 0xFFFF;
        int col = ei[t*2*NE + NE + idx];
        pcolt[j] = col | (t << 16);
        pev[j] = edge_value[pe];
    }
}

// ---------------- dense pieces ----------------

// X_[c][n][d] = sum_f X[n][f] * Ws[c][f][d]
__global__ void k_proj(const float* __restrict__ X, const float* __restrict__ Ws,
                       float* __restrict__ Xp) {
    int g = blockIdx.x*blockDim.x + threadIdx.x;   // NCH*N*64 threads
    int d = g & 63;
    int n = (g >> 6) & (N_NODES - 1);
    int c = g >> 17;
    const float* xr = X + n*W_IN;
    const float* wc = Ws + c*W_IN*W_OUT + d;
    float a0=0.f, a1=0.f, a2=0.f, a3=0.f;
    for (int f = 0; f < W_IN; f += 4) {
        a0 += xr[f+0] * wc[(f+0)*W_OUT];
        a1 += xr[f+1] * wc[(f+1)*W_OUT];
        a2 += xr[f+2] * wc[(f+2)*W_OUT];
        a3 += xr[f+3] * wc[(f+3)*W_OUT];
    }
    Xp[g] = (a0+a1) + (a2+a3);
}

// ---------------- SpMM: y[c][row][*] = sum_edges val * x[...][col][*] ----------------
// WIDTH in {64,16,1}. SHARED_X: x is [N][WIDTH] (same for both channels) vs [C][N][WIDTH].
// ONES (WIDTH==1 only): treat x as all-ones.
template<int WIDTH, bool SHARED_X, bool ONES>
__global__ void k_spmm(const int* __restrict__ row_start, const int* __restrict__ pcolt,
                       const float* __restrict__ pev, const float* __restrict__ filtl,
                       const float* __restrict__ x, float* __restrict__ y) {
    int w    = blockIdx.x*4 + (threadIdx.x >> 6);   // wave id in [0, NCH*N)
    int lane = threadIdx.x & 63;
    int c    = w >> 11;
    int row  = w & (N_NODES - 1);
    float f0 = filtl[c*NET+0], f1 = filtl[c*NET+1], f2 = filtl[c*NET+2];
    int begin = row_start[row], end = row_start[row+1];
    const float* xb = SHARED_X ? x : (x + (size_t)c * N_NODES * WIDTH);
    float acc = 0.f;

    if (WIDTH == 64) {
        for (int j0 = begin; j0 < end; j0 += 64) {
            int jj = j0 + lane;
            int ct = 0; float ev = 0.f;
            if (jj < end) { ct = pcolt[jj]; ev = pev[jj]; }
            int t = ct >> 16;
            float v = ev * (t == 0 ? f0 : (t == 1 ? f1 : f2));
            int m = min(64, end - j0);
            for (int k = 0; k < m; k++) {
                int   ck = __shfl(ct, k) & 0xFFFF;
                float vk = __shfl(v, k);
                acc += vk * xb[ck*64 + lane];
            }
        }
        y[((size_t)c*N_NODES + row)*64 + lane] = acc;
    } else if (WIDTH == 16) {
        int d = lane & 15, sub = lane >> 4;
        for (int j0 = begin; j0 < end; j0 += 64) {
            int jj = j0 + lane;
            int ct = 0; float ev = 0.f;
            if (jj < end) { ct = pcolt[jj]; ev = pev[jj]; }
            int t = ct >> 16;
            float v = ev * (t == 0 ? f0 : (t == 1 ? f1 : f2));
            int m = min(64, end - j0);
            for (int k = 0; k < m; k += 4) {
                int ks = k + sub;                 // <= 63 always (m<=64, k multiple of 4)
                int   ck = __shfl(ct, ks) & 0xFFFF;
                float vk = __shfl(v, ks);         // 0 for padded edges
                acc += vk * xb[ck*16 + d];
            }
        }
        acc += __shfl_xor(acc, 16);
        acc += __shfl_xor(acc, 32);
        if (lane < 16) y[((size_t)c*N_NODES + row)*16 + lane] = acc;
    } else { // WIDTH == 1
        for (int j0 = begin; j0 < end; j0 += 64) {
            int jj = j0 + lane;
            if (jj < end) {
                int ct = pcolt[jj]; float ev = pev[jj];
                int t = ct >> 16;
                float v = ev * (t == 0 ? f0 : (t == 1 ? f1 : f2));
                int ck = ct & 0xFFFF;
                float xv = ONES ? 1.0f : xb[ck];
                acc += v * xv;
            }
        }
        #pragma unroll
        for (int o = 32; o >= 1; o >>= 1) acc += __shfl_xor(acc, o);
        if (lane == 0) y[(size_t)c*N_NODES + row] = acc;
    }
}

// Hc = mean_c relu(0.5*X_ + 0.5*H)
__global__ void k_blend(const float* __restrict__ Xp, const float* __restrict__ H,
                        float* __restrict__ Hc) {
    int g = blockIdx.x*blockDim.x + threadIdx.x;   // N*64
    if (g < N_NODES*64) {
        float v0 = 0.5f*Xp[g]              + 0.5f*H[g];
        float v1 = 0.5f*Xp[g + N_NODES*64] + 0.5f*H[g + N_NODES*64];
        v0 = fmaxf(v0, 0.f); v1 = fmaxf(v1, 0.f);
        Hc[g] = 0.5f*(v0 + v1);
    }
}

__global__ void k_dinv(const float* __restrict__ s1, float* __restrict__ dinv) {
    int n = blockIdx.x*blockDim.x + threadIdx.x;
    if (n < N_NODES) {
        float deg = 1.0f + s1[n] + s1[N_NODES + n];
        dinv[n] = deg > 0.f ? rsqrtf(deg) : 0.f;
    }
}

// M1d = dinv * (Hc @ w1)   [N,16]
__global__ void k_m1(const float* __restrict__ Hc, const float* __restrict__ w1,
                     const float* __restrict__ dinv, float* __restrict__ M1d) {
    int g = blockIdx.x*blockDim.x + threadIdx.x;   // N*16
    int j = g & 15, n = g >> 4;
    float acc = 0.f;
    #pragma unroll 8
    for (int d = 0; d < 64; d++) acc += Hc[n*64 + d] * w1[d*16 + j];
    M1d[g] = dinv[n] * acc;
}

// h1 = relu(dinv*(P0+P1+M1d) + b1)
__global__ void k_h1(const float* __restrict__ P, const float* __restrict__ M1d,
                     const float* __restrict__ dinv, const float* __restrict__ b1,
                     float* __restrict__ h1) {
    int g = blockIdx.x*blockDim.x + threadIdx.x;   // N*16
    int j = g & 15, n = g >> 4;
    float v = dinv[n] * (P[g] + P[N_NODES*16 + g] + M1d[g]) + b1[j];
    h1[g] = fmaxf(v, 0.f);
}

// M2d = dinv * (h1 @ w2)   [N,64]
__global__ void k_m2(const float* __restrict__ h1, const float* __restrict__ w2,
                     const float* __restrict__ dinv, float* __restrict__ M2d) {
    int g = blockIdx.x*blockDim.x + threadIdx.x;   // N*64
    int d = g & 63, n = g >> 6;
    float acc = 0.f;
    #pragma unroll
    for (int j = 0; j < 16; j++) acc += h1[n*16 + j] * w2[j*64 + d];
    M2d[g] = dinv[n] * acc;
}

// h2 = dinv*(R0+R1+M2d)+b2 ; hout = log_softmax(h2) per row (64 cols)
__global__ void k_lsm(const float* __restrict__ R, const float* __restrict__ M2d,
                      const float* __restrict__ dinv, const float* __restrict__ b2,
                      float* __restrict__ hout) {
    int n    = blockIdx.x*4 + (threadIdx.x >> 6);
    int lane = threadIdx.x & 63;
    float v = dinv[n] * (R[n*64 + lane] + R[N_NODES*64 + n*64 + lane] + M2d[n*64 + lane])
              + b2[lane];
    float mx = v;
    #pragma unroll
    for (int o = 1; o < 64; o <<= 1) mx = fmaxf(mx, __shfl_xor(mx, o));
    float s = expf(v - mx);
    #pragma unroll
    for (int o = 1; o < 64; o <<= 1) s += __shfl_xor(s, o);
    hout[n*64 + lane] = v - mx - logf(s);
}

// y = hout[tgt] @ lin_w + lin_b   [NTGT,16]
__global__ void k_out(const float* __restrict__ hout, const int* __restrict__ tgt,
                      const float* __restrict__ lin_w, const float* __restrict__ lin_b,
                      float* __restrict__ y) {
    int g = blockIdx.x*blockDim.x + threadIdx.x;   // NTGT*16
    int k = g & 15, i = g >> 4;
    int node = tgt[i];
    float acc = 0.f;
    #pragma unroll 8
    for (int d = 0; d < 64; d++) acc += hout[node*64 + d] * lin_w[d*16 + k];
    y[g] = acc + lin_b[k];
}

// ---------------- launch ----------------

extern "C" void kernel_launch(void* const* d_in, const int* in_sizes, int n_in,
                              void* d_out, int out_size, void* d_ws, size_t ws_size,
                              hipStream_t stream) {
    const float* X          = (const float*)d_in[0];
    const float* edge_value = (const float*)d_in[1];
    const float* conv_w     = (const float*)d_in[2];
    const float* Ws         = (const float*)d_in[3];
    const float* w1         = (const float*)d_in[4];
    const float* b1         = (const float*)d_in[5];
    const float* w2         = (const float*)d_in[6];
    const float* b2         = (const float*)d_in[7];
    const float* lin_w      = (const float*)d_in[8];
    const float* lin_b      = (const float*)d_in[9];
    const int*   ei         = (const int*)d_in[10];
    const int*   tgt        = (const int*)d_in[11];
    float* out = (float*)d_out;

    float* base = (float*)d_ws;
    float* filt      = base;                       // 64
    int*   counts    = (int*)(base + 64);          // 2048
    int*   row_start = (int*)(base + 64 + 2048);   // 2112 (2049 used)
    int*   cursor    = (int*)(base + 64 + 2048 + 2112); // 2048
    int*   perm      = (int*)(base + 6272);        // 196608
    int*   pcolt     = (int*)(base + 6272 + TE);   // 196608
    float* pev       = base + 6272 + 2*TE;         // 196608
    float* Xp        = base + 6272 + 3*TE;         // 262144
    float* Hh1       = Xp  + NCH*N_NODES*64;       // 262144
    float* Hh2       = Hh1 + NCH*N_NODES*64;       // 262144
    float* Hc        = Hh2 + NCH*N_NODES*64;       // 131072
    float* s0        = Hc  + N_NODES*64;           // 4096
    float* s1v       = s0  + NCH*N_NODES;          // 4096
    float* dinv      = s1v + NCH*N_NODES;          // 2048
    float* M1d       = dinv + N_NODES;             // 32768
    float* Ub        = M1d + N_NODES*16;           // 65536
    float* Pb        = Ub  + NCH*N_NODES*16;       // 65536
    float* h1b       = Pb  + NCH*N_NODES*16;       // 32768
    float* M2d       = h1b + N_NODES*16;           // 131072
    float* hout      = M2d + N_NODES*64;           // 131072
    float* Vb        = Hh1;                        // reuse (free after k_blend)
    float* Rb        = Hh2;                        // reuse

    const float* filt_l0 = filt;
    const float* filt_l1 = filt + NCH*NET;

    // setup
    k_filt   <<<1, 64, 0, stream>>>(conv_w, filt);
    k_zero   <<<8, 256, 0, stream>>>(counts, N_NODES);
    k_hist   <<<TE/256, 256, 0, stream>>>(ei, counts);
    k_scan   <<<1, 256, 0, stream>>>(counts, row_start, cursor);
    k_scatter<<<TE/256, 256, 0, stream>>>(ei, cursor, perm);
    k_edges  <<<TE/256, 256, 0, stream>>>(ei, edge_value, perm, pcolt, pev);

    // per-channel projection
    k_proj<<<NCH*N_NODES*64/256, 256, 0, stream>>>(X, Ws, Xp);

    // H chain: H = mats1 @ mats0 @ X_
    k_spmm<64,false,false><<<NCH*N_NODES/4, 256, 0, stream>>>(row_start, pcolt, pev, filt_l0, Xp,  Hh1);
    k_spmm<64,false,false><<<NCH*N_NODES/4, 256, 0, stream>>>(row_start, pcolt, pev, filt_l1, Hh1, Hh2);

    // channel aggregation
    k_blend<<<N_NODES*64/256, 256, 0, stream>>>(Xp, Hh2, Hc);

    // deg = 1 + sum_c mats1_c @ (mats0_c @ 1) ; dinv = rsqrt(deg)
    k_spmm<1,false,true ><<<NCH*N_NODES/4, 256, 0, stream>>>(row_start, pcolt, pev, filt_l0, s0, s0);
    k_spmm<1,false,false><<<NCH*N_NODES/4, 256, 0, stream>>>(row_start, pcolt, pev, filt_l1, s0, s1v);
    k_dinv<<<8, 256, 0, stream>>>(s1v, dinv);

    // GCN layer 1 (width 16)
    k_m1<<<N_NODES*16/256, 256, 0, stream>>>(Hc, w1, dinv, M1d);
    k_spmm<16,true ,false><<<NCH*N_NODES/4, 256, 0, stream>>>(row_start, pcolt, pev, filt_l0, M1d, Ub);
    k_spmm<16,false,false><<<NCH*N_NODES/4, 256, 0, stream>>>(row_start, pcolt, pev, filt_l1, Ub,  Pb);
    k_h1<<<N_NODES*16/256, 256, 0, stream>>>(Pb, M1d, dinv, b1, h1b);

    // GCN layer 2 (width 64)
    k_m2<<<N_NODES*64/256, 256, 0, stream>>>(h1b, w2, dinv, M2d);
    k_spmm<64,true ,false><<<NCH*N_NODES/4, 256, 0, stream>>>(row_start, pcolt, pev, filt_l0, M2d, Vb);
    k_spmm<64,false,false><<<NCH*N_NODES/4, 256, 0, stream>>>(row_start, pcolt, pev, filt_l1, Vb,  Rb);

    // log_softmax + head
    k_lsm<<<N_NODES/4, 256, 0, stream>>>(Rb, M2d, dinv, b2, hout);
    k_out<<<NTGT*16/256, 256, 0, stream>>>(hout, tgt, lin_w, lin_b, out);
}

// Round 2
// 243.451 us; speedup vs baseline: 1.1801x; 1.1801x over previous
//
#include <hip/hip_runtime.h>
#include <math.h>

#define N_NODES 2048
#define NCH 2
#define NET 3
#define NE 65536
#define TE 196608   /* NET*NE */
#define W_IN 256
#define W_OUT 64
#define NTGT 512

#define RFL(x) __builtin_amdgcn_readfirstlane(x)

// ---------------- A: zero counts + filt + per-channel projection ----------------
__global__ __launch_bounds__(256) void k_init(
    const float* __restrict__ conv_w, const float* __restrict__ X,
    const float* __restrict__ Ws, float* __restrict__ filt,
    int* __restrict__ counts, float* __restrict__ Xp) {
    int b = blockIdx.x, tid = threadIdx.x;
    if (b == 0) {
        #pragma unroll
        for (int k = 0; k < 8; k++) counts[tid*8 + k] = 0;
        if (tid < 4) {
            float a = conv_w[tid*3+0], bb = conv_w[tid*3+1], cc = conv_w[tid*3+2];
            float m = fmaxf(a, fmaxf(bb, cc));
            float ea = expf(a-m), eb = expf(bb-m), ec = expf(cc-m);
            float s = ea + eb + ec;
            filt[tid*3+0] = ea/s; filt[tid*3+1] = eb/s; filt[tid*3+2] = ec/s;
        }
    } else {
        int g = (b-1)*256 + tid;            // NCH*N*64 total
        int d = g & 63;
        int n = (g >> 6) & (N_NODES - 1);
        int c = g >> 17;
        const float* xr = X + n*W_IN;
        const float* wc = Ws + c*W_IN*W_OUT + d;
        float a0=0.f, a1=0.f, a2=0.f, a3=0.f;
        for (int f = 0; f < W_IN; f += 4) {
            a0 += xr[f+0] * wc[(f+0)*W_OUT];
            a1 += xr[f+1] * wc[(f+1)*W_OUT];
            a2 += xr[f+2] * wc[(f+2)*W_OUT];
            a3 += xr[f+3] * wc[(f+3)*W_OUT];
        }
        Xp[g] = (a0+a1) + (a2+a3);
    }
}

// ---------------- B: histogram of row degrees ----------------
__global__ __launch_bounds__(256) void k_hist(const int* __restrict__ ei,
                                              int* __restrict__ counts) {
    int e = blockIdx.x*256 + threadIdx.x;
    int t = e >> 16, idx = e & 0xFFFF;
    int row = ei[t*2*NE + idx];
    atomicAdd(&counts[row], 1);
}

// ---------------- C: exclusive scan -> row_start, cursor ----------------
__global__ __launch_bounds__(256) void k_scan(const int* __restrict__ counts,
                                              int* __restrict__ row_start,
                                              int* __restrict__ cursor) {
    __shared__ int part[256];
    int tid = threadIdx.x;
    int loc[8]; int s = 0;
    #pragma unroll
    for (int k = 0; k < 8; k++) { loc[k] = s; s += counts[tid*8 + k]; }
    part[tid] = s;
    __syncthreads();
    for (int off = 1; off < 256; off <<= 1) {
        int v = (tid >= off) ? part[tid - off] : 0;
        __syncthreads();
        part[tid] += v;
        __syncthreads();
    }
    int base = tid ? part[tid-1] : 0;
    #pragma unroll
    for (int k = 0; k < 8; k++) {
        int rs = base + loc[k];
        row_start[tid*8 + k] = rs;
        cursor[tid*8 + k] = rs;
    }
    if (tid == 255) row_start[N_NODES] = part[255];
}

// ---------------- D: scatter + build pre-scaled edge values ----------------
// ev4[pos] = ev * (filt[l0,c0], filt[l0,c1], filt[l1,c0], filt[l1,c1])
__global__ __launch_bounds__(256) void k_build(
    const int* __restrict__ ei, const float* __restrict__ edge_value,
    const float* __restrict__ filt, int* __restrict__ cursor,
    int* __restrict__ ecol, float4* __restrict__ ev4) {
    int e = blockIdx.x*256 + threadIdx.x;
    int t = e >> 16, idx = e & 0xFFFF;
    int row = ei[t*2*NE + idx];
    int col = ei[t*2*NE + NE + idx];
    float ev = edge_value[e];
    int pos = atomicAdd(&cursor[row], 1);
    float f00 = filt[t], f01 = filt[3+t], f10 = filt[6+t], f11 = filt[9+t];
    ecol[pos] = col;
    ev4[pos] = make_float4(ev*f00, ev*f01, ev*f10, ev*f11);
}

// ---------------- H chain pass 1: H1 = mats_l0 @ Xp, plus s0 = rowsum ----------------
__global__ __launch_bounds__(256) void k_h_l0(
    const int* __restrict__ rs, const int* __restrict__ ecol,
    const float2* __restrict__ ev2, const float* __restrict__ Xp,
    float* __restrict__ H1, float* __restrict__ s0) {
    int w = RFL(blockIdx.x*4 + (threadIdx.x >> 6));
    int lane = threadIdx.x & 63;
    int c = w >> 11, row = w & (N_NODES - 1);
    int begin = rs[row], end = rs[row+1];
    const float* xb = Xp + c*(N_NODES*64);
    float a0=0.f,a1=0.f,a2=0.f,a3=0.f, vs=0.f;
    int j = begin;
    for (; j+4 <= end; j += 4) {
        int c0=ecol[j], c1=ecol[j+1], c2=ecol[j+2], c3=ecol[j+3];
        float2 e0=ev2[2*j], e1=ev2[2*j+2], e2=ev2[2*j+4], e3=ev2[2*j+6];
        float v0 = c ? e0.y : e0.x, v1 = c ? e1.y : e1.x;
        float v2 = c ? e2.y : e2.x, v3 = c ? e3.y : e3.x;
        a0 += v0 * xb[c0*64+lane];
        a1 += v1 * xb[c1*64+lane];
        a2 += v2 * xb[c2*64+lane];
        a3 += v3 * xb[c3*64+lane];
        vs += (v0+v1) + (v2+v3);
    }
    for (; j < end; ++j) {
        int c0 = ecol[j]; float2 e0 = ev2[2*j];
        float v0 = c ? e0.y : e0.x;
        a0 += v0 * xb[c0*64+lane];
        vs += v0;
    }
    H1[(size_t)w*64 + lane] = (a0+a1) + (a2+a3);
    if (lane == 0) s0[w] = vs;
}

// ---------------- H chain pass 2: H2 = mats_l1 @ H1, plus s1 = mats_l1 @ s0 ----------------
__global__ __launch_bounds__(256) void k_h_l1(
    const int* __restrict__ rs, const int* __restrict__ ecol,
    const float2* __restrict__ ev2, const float* __restrict__ H1,
    const float* __restrict__ s0, float* __restrict__ H2, float* __restrict__ s1) {
    int w = RFL(blockIdx.x*4 + (threadIdx.x >> 6));
    int lane = threadIdx.x & 63;
    int c = w >> 11, row = w & (N_NODES - 1);
    int begin = rs[row], end = rs[row+1];
    const float* xb  = H1 + c*(N_NODES*64);
    const float* s0c = s0 + c*N_NODES;
    float a0=0.f,a1=0.f,a2=0.f,a3=0.f, sv=0.f;
    int j = begin;
    for (; j+4 <= end; j += 4) {
        int c0=ecol[j], c1=ecol[j+1], c2=ecol[j+2], c3=ecol[j+3];
        float2 e0=ev2[2*j+1], e1=ev2[2*j+3], e2=ev2[2*j+5], e3=ev2[2*j+7];
        float v0 = c ? e0.y : e0.x, v1 = c ? e1.y : e1.x;
        float v2 = c ? e2.y : e2.x, v3 = c ? e3.y : e3.x;
        a0 += v0 * xb[c0*64+lane];
        a1 += v1 * xb[c1*64+lane];
        a2 += v2 * xb[c2*64+lane];
        a3 += v3 * xb[c3*64+lane];
        sv += v0*s0c[c0] + v1*s0c[c1] + v2*s0c[c2] + v3*s0c[c3];
    }
    for (; j < end; ++j) {
        int c0 = ecol[j]; float2 e0 = ev2[2*j+1];
        float v0 = c ? e0.y : e0.x;
        a0 += v0 * xb[c0*64+lane];
        sv += v0 * s0c[c0];
    }
    H2[(size_t)w*64 + lane] = (a0+a1) + (a2+a3);
    if (lane == 0) s1[w] = sv;
}

// ---------------- blend + dinv + M1d = dinv*(Hc @ w1) ----------------
__global__ __launch_bounds__(256) void k_bm1(
    const float* __restrict__ Xp, const float* __restrict__ H2,
    const float* __restrict__ s1, const float* __restrict__ w1,
    float* __restrict__ dinv, float* __restrict__ M1d) {
    int n = RFL(blockIdx.x*4 + (threadIdx.x >> 6));
    int lane = threadIdx.x & 63;
    float x0 = Xp[n*64+lane], x1 = Xp[N_NODES*64 + n*64+lane];
    float h0 = H2[n*64+lane], h1 = H2[N_NODES*64 + n*64+lane];
    float hc = 0.5f*(fmaxf(0.5f*x0 + 0.5f*h0, 0.f) + fmaxf(0.5f*x1 + 0.5f*h1, 0.f));
    float dv = rsqrtf(1.0f + s1[n] + s1[N_NODES+n]);
    if (lane == 0) dinv[n] = dv;
    float p[16];
    #pragma unroll
    for (int jj = 0; jj < 16; jj++) p[jj] = hc * w1[lane*16 + jj];
    #pragma unroll
    for (int jj = 0; jj < 16; jj++) {
        #pragma unroll
        for (int off = 1; off < 64; off <<= 1) p[jj] += __shfl_xor(p[jj], off);
    }
    if (lane < 16) {
        float outv = 0.f;
        #pragma unroll
        for (int jj = 0; jj < 16; jj++) if (lane == jj) outv = p[jj];
        M1d[n*16 + lane] = dv * outv;
    }
}

// ---------------- GCN width-16 pass 1: U_c = mats_l0_c @ M1d (shared x) ----------------
__global__ __launch_bounds__(256) void k_g1a(
    const int* __restrict__ rs, const int* __restrict__ ecol,
    const float2* __restrict__ ev2, const float* __restrict__ M1d,
    float* __restrict__ U) {
    int r = RFL(blockIdx.x*4 + (threadIdx.x >> 6));
    int lane = threadIdx.x & 63;
    int d = lane & 15;
    bool ch = (lane >> 4) & 1;
    bool hi = lane >= 32;
    int begin = rs[r], end = rs[r+1];
    float acc = 0.f;
    int j = begin;
    for (; j+2 <= end; j += 2) {
        int c0 = ecol[j], c1 = ecol[j+1];
        float2 e0 = ev2[2*j], e1 = ev2[2*j+2];
        float t0 = ch ? e0.y : e0.x;
        float t1 = ch ? e1.y : e1.x;
        float v  = hi ? t1 : t0;
        int col  = hi ? c1 : c0;
        acc += v * M1d[col*16 + d];
    }
    if (j < end) {
        int c0 = ecol[j]; float2 e0 = ev2[2*j];
        float v = hi ? 0.f : (ch ? e0.y : e0.x);
        acc += v * M1d[c0*16 + d];
    }
    acc += __shfl_xor(acc, 32);
    if (lane < 32) U[(ch ? N_NODES*16 : 0) + r*16 + d] = acc;
}

// ---------------- GCN width-16 pass 2 + h1 + M2d = dinv*(h1 @ w2) ----------------
__global__ __launch_bounds__(256) void k_g1b(
    const int* __restrict__ rs, const int* __restrict__ ecol,
    const float2* __restrict__ ev2, const float* __restrict__ U,
    const float* __restrict__ M1d, const float* __restrict__ dinv,
    const float* __restrict__ b1, const float* __restrict__ w2,
    float* __restrict__ M2d) {
    int r = RFL(blockIdx.x*4 + (threadIdx.x >> 6));
    int lane = threadIdx.x & 63;
    int d = lane & 15;
    bool ch = (lane >> 4) & 1;
    bool hi = lane >= 32;
    int chOff = ch ? N_NODES*16 : 0;
    int begin = rs[r], end = rs[r+1];
    float acc = 0.f;
    int j = begin;
    for (; j+2 <= end; j += 2) {
        int c0 = ecol[j], c1 = ecol[j+1];
        float2 e0 = ev2[2*j+1], e1 = ev2[2*j+3];
        float t0 = ch ? e0.y : e0.x;
        float t1 = ch ? e1.y : e1.x;
        float v  = hi ? t1 : t0;
        int col  = hi ? c1 : c0;
        acc += v * U[chOff + col*16 + d];
    }
    if (j < end) {
        int c0 = ecol[j]; float2 e0 = ev2[2*j+1];
        float v = hi ? 0.f : (ch ? e0.y : e0.x);
        acc += v * U[chOff + c0*16 + d];
    }
    acc += __shfl_xor(acc, 32);
    acc += __shfl_xor(acc, 16);
    float dv = dinv[r];
    float hv = fmaxf(dv*(acc + M1d[r*16 + d]) + b1[d], 0.f);
    float m2 = 0.f;
    #pragma unroll
    for (int jj = 0; jj < 16; jj++) m2 += __shfl(hv, jj) * w2[jj*64 + lane];
    M2d[r*64 + lane] = dv * m2;
}

// ---------------- GCN width-64 pass 1: V_c = mats_l0_c @ M2d (shared x, 2 outs) ----------------
__global__ __launch_bounds__(256) void k_g2a(
    const int* __restrict__ rs, const int* __restrict__ ecol,
    const float2* __restrict__ ev2, const float* __restrict__ M2d,
    float* __restrict__ V) {
    int r = RFL(blockIdx.x*4 + (threadIdx.x >> 6));
    int lane = threadIdx.x & 63;
    int begin = rs[r], end = rs[r+1];
    float a00=0.f,a01=0.f,a10=0.f,a11=0.f;
    int j = begin;
    for (; j+2 <= end; j += 2) {
        int c0 = ecol[j], c1 = ecol[j+1];
        float2 e0 = ev2[2*j], e1 = ev2[2*j+2];
        float x0 = M2d[c0*64 + lane], x1 = M2d[c1*64 + lane];
        a00 += e0.x*x0; a01 += e0.y*x0;
        a10 += e1.x*x1; a11 += e1.y*x1;
    }
    if (j < end) {
        int c0 = ecol[j]; float2 e0 = ev2[2*j];
        float x0 = M2d[c0*64 + lane];
        a00 += e0.x*x0; a01 += e0.y*x0;
    }
    V[(size_t)r*64 + lane] = a00 + a10;
    V[(size_t)N_NODES*64 + r*64 + lane] = a01 + a11;
}

// ---------------- GCN width-64 pass 2 + log_softmax ----------------
__global__ __launch_bounds__(256) void k_g2b(
    const int* __restrict__ rs, const int* __restrict__ ecol,
    const float2* __restrict__ ev2, const float* __restrict__ V,
    const float* __restrict__ M2d, const float* __restrict__ dinv,
    const float* __restrict__ b2, float* __restrict__ hout) {
    int r = RFL(blockIdx.x*4 + (threadIdx.x >> 6));
    int lane = threadIdx.x & 63;
    int begin = rs[r], end = rs[r+1];
    float a0=0.f, a1=0.f;
    int j = begin;
    for (; j+2 <= end; j += 2) {
        int c0 = ecol[j], c1 = ecol[j+1];
        float2 e0 = ev2[2*j+1], e1 = ev2[2*j+3];
        a0 += e0.x*V[c0*64+lane] + e0.y*V[N_NODES*64 + c0*64+lane];
        a1 += e1.x*V[c1*64+lane] + e1.y*V[N_NODES*64 + c1*64+lane];
    }
    if (j < end) {
        int c0 = ecol[j]; float2 e0 = ev2[2*j+1];
        a0 += e0.x*V[c0*64+lane] + e0.y*V[N_NODES*64 + c0*64+lane];
    }
    float v = dinv[r]*(a0 + a1 + M2d[r*64 + lane]) + b2[lane];
    float mx = v;
    #pragma unroll
    for (int o = 1; o < 64; o <<= 1) mx = fmaxf(mx, __shfl_xor(mx, o));
    float s = expf(v - mx);
    #pragma unroll
    for (int o = 1; o < 64; o <<= 1) s += __shfl_xor(s, o);
    hout[r*64 + lane] = v - mx - logf(s);
}

// ---------------- head ----------------
__global__ __launch_bounds__(256) void k_out(
    const float* __restrict__ hout, const int* __restrict__ tgt,
    const float* __restrict__ lin_w, const float* __restrict__ lin_b,
    float* __restrict__ y) {
    int g = blockIdx.x*256 + threadIdx.x;   // NTGT*16
    int k = g & 15, i = g >> 4;
    int node = tgt[i];
    float acc = 0.f;
    #pragma unroll 8
    for (int d = 0; d < 64; d++) acc += hout[node*64 + d] * lin_w[d*16 + k];
    y[g] = acc + lin_b[k];
}

// ---------------- launch ----------------
extern "C" void kernel_launch(void* const* d_in, const int* in_sizes, int n_in,
                              void* d_out, int out_size, void* d_ws, size_t ws_size,
                              hipStream_t stream) {
    const float* X          = (const float*)d_in[0];
    const float* edge_value = (const float*)d_in[1];
    const float* conv_w     = (const float*)d_in[2];
    const float* Ws         = (const float*)d_in[3];
    const float* w1         = (const float*)d_in[4];
    const float* b1         = (const float*)d_in[5];
    const float* w2         = (const float*)d_in[6];
    const float* b2         = (const float*)d_in[7];
    const float* lin_w      = (const float*)d_in[8];
    const float* lin_b      = (const float*)d_in[9];
    const int*   ei         = (const int*)d_in[10];
    const int*   tgt        = (const int*)d_in[11];
    float* out = (float*)d_out;

    float* base = (float*)d_ws;
    float*  filt      = base + 0;                     // 16
    int*    counts    = (int*)(base + 16);            // 2048
    int*    row_start = (int*)(base + 2064);          // 2049 (pad to 2064)
    int*    cursor    = (int*)(base + 4128);          // 2048
    int*    ecol      = (int*)(base + 6176);          // TE
    float*  evbuf     = base + 6176 + TE;             // 4*TE  (16B aligned)
    float4* ev4       = (float4*)evbuf;
    const float2* ev2 = (const float2*)evbuf;
    float*  Xp   = evbuf + 4*TE;                      // 262144
    float*  Hh1  = Xp   + NCH*N_NODES*64;             // 262144
    float*  Hh2  = Hh1  + NCH*N_NODES*64;             // 262144
    float*  s0   = Hh2  + NCH*N_NODES*64;             // 4096
    float*  s1   = s0   + NCH*N_NODES;                // 4096
    float*  dinv = s1   + NCH*N_NODES;                // 2048
    float*  M1d  = dinv + N_NODES;                    // 32768
    float*  U    = M1d  + N_NODES*16;                 // 65536
    float*  M2d  = U    + NCH*N_NODES*16;             // 131072
    float*  V    = M2d  + N_NODES*64;                 // 262144
    float*  hout = V    + NCH*N_NODES*64;             // 131072

    k_init <<<1 + NCH*N_NODES*64/256, 256, 0, stream>>>(conv_w, X, Ws, filt, counts, Xp);
    k_hist <<<TE/256, 256, 0, stream>>>(ei, counts);
    k_scan <<<1, 256, 0, stream>>>(counts, row_start, cursor);
    k_build<<<TE/256, 256, 0, stream>>>(ei, edge_value, filt, cursor, ecol, ev4);

    k_h_l0<<<NCH*N_NODES/4, 256, 0, stream>>>(row_start, ecol, ev2, Xp, Hh1, s0);
    k_h_l1<<<NCH*N_NODES/4, 256, 0, stream>>>(row_start, ecol, ev2, Hh1, s0, Hh2, s1);

    k_bm1<<<N_NODES/4, 256, 0, stream>>>(Xp, Hh2, s1, w1, dinv, M1d);

    k_g1a<<<N_NODES/4, 256, 0, stream>>>(row_start, ecol, ev2, M1d, U);
    k_g1b<<<N_NODES/4, 256, 0, stream>>>(row_start, ecol, ev2, U, M1d, dinv, b1, w2, M2d);

    k_g2a<<<N_NODES/4, 256, 0, stream>>>(row_start, ecol, ev2, M2d, V);
    k_g2b<<<N_NODES/4, 256, 0, stream>>>(row_start, ecol, ev2, V, M2d, dinv, b2, hout);

    k_out<<<NTGT*16/256, 256, 0, stream>>>(hout, tgt, lin_w, lin_b, out);
}